// Round 1
// baseline (1223.672 us; speedup 1.0000x reference)
//
#include <hip/hip_runtime.h>

namespace {
constexpr int kB  = 8;
constexpr int kC  = 128;
constexpr int kC2 = 64;
constexpr int kF  = 256;
constexpr int kT  = 128;
constexpr int kD  = 32;
}

// One block per (b, f). 256 threads = 4 waves. 64KB static LDS -> 2 blocks/CU.
//
// Phases (all fp32):
//  1. K/Q projections: kq[g][d][c], g in {kr, ki, qr, qi}           (32KB)
//  2. P = K Q^T (complex), softmax over c -> sW[ri][c][e]           (32KB)
//  3. U_r = Xr^T W_r - Xi^T W_i, U_i = Xr^T W_i + Xi^T W_r (regs),
//     then overwrite lds with U[ri][e][s]                           (64KB)
//  4. o_r = Wv U_r ; o_i = Wv U_i + 2 bv ; coalesced store.
__global__ __launch_bounds__(256, 2)
void chanattn_f32(const float* __restrict__ x,
                  const float* __restrict__ Wk, const float* __restrict__ bk,
                  const float* __restrict__ Wq, const float* __restrict__ bq,
                  const float* __restrict__ Wv, const float* __restrict__ bv,
                  float* __restrict__ out)
{
    __shared__ float lds[16384];            // 64 KB
    float* kq = lds;                        // [4][32][64] : g*2048 + d*64 + c
    float* sW = lds + 8192;                 // [2][64][64] : ri*4096 + c*64 + e

    const int f   = blockIdx.x;
    const int b   = blockIdx.y;
    const int tid = threadIdx.x;
    const size_t cstride = (size_t)kF * kT; // stride between channels in x
    const float* xb = x + ((size_t)b * kC * kF + f) * kT;  // xb[c*cstride + t]

    // ---------------- Phase 1: K/Q projections ----------------
    {
        const int c = tid & 63;
        const int g = tid >> 6;                 // 0=k_r 1=k_i 2=q_r 3=q_i
        const float* xrow = xb + (size_t)(c + ((g & 1) ? kC2 : 0)) * cstride;
        const float* Wm = (g < 2) ? Wk : Wq;
        const float* bm = (g < 2) ? bk : bq;
        float acc[kD];
        #pragma unroll
        for (int d = 0; d < kD; ++d) acc[d] = 0.f;
        for (int tc = 0; tc < kT; tc += 4) {
            const float4 xv = *reinterpret_cast<const float4*>(xrow + tc);
            #pragma unroll
            for (int d = 0; d < kD; ++d) {
                const float4 wv = *reinterpret_cast<const float4*>(Wm + d * kT + tc);
                acc[d] += xv.x * wv.x + xv.y * wv.y + xv.z * wv.z + xv.w * wv.w;
            }
        }
        #pragma unroll
        for (int d = 0; d < kD; ++d)
            kq[g * 2048 + d * 64 + c] = acc[d] + bm[d];
    }
    __syncthreads();

    // ---------------- Phase 2: P + softmax over c ----------------
    {
        const int e  = tid >> 2;                // 0..63
        const int cg = tid & 3;                 // 4 threads per e column
        float qr[kD], qi[kD];
        #pragma unroll
        for (int d = 0; d < kD; ++d) {
            qr[d] = kq[2 * 2048 + d * 64 + e];
            qi[d] = kq[3 * 2048 + d * 64 + e];
        }
        float pr[16], pi[16];
        #pragma unroll
        for (int j = 0; j < 16; ++j) {
            const int c = cg + 4 * j;
            float prr = 0.f, pii = 0.f, pri = 0.f, pir = 0.f;
            #pragma unroll
            for (int d = 0; d < kD; ++d) {
                const float kr = kq[0 * 2048 + d * 64 + c];
                const float ki = kq[1 * 2048 + d * 64 + c];
                prr += kr * qr[d];
                pii += ki * qi[d];
                pri += kr * qi[d];
                pir += ki * qr[d];
            }
            pr[j] = prr - pii;                  // P_r[c, e]
            pi[j] = pri + pir;                  // P_i[c, e]
        }
        // softmax over c: 16 local values x 4 adjacent lanes
        float mr = pr[0], mi = pi[0];
        #pragma unroll
        for (int j = 1; j < 16; ++j) { mr = fmaxf(mr, pr[j]); mi = fmaxf(mi, pi[j]); }
        mr = fmaxf(mr, __shfl_xor(mr, 1)); mr = fmaxf(mr, __shfl_xor(mr, 2));
        mi = fmaxf(mi, __shfl_xor(mi, 1)); mi = fmaxf(mi, __shfl_xor(mi, 2));
        float sr = 0.f, si = 0.f;
        #pragma unroll
        for (int j = 0; j < 16; ++j) {
            pr[j] = __expf(pr[j] - mr);
            pi[j] = __expf(pi[j] - mi);
            sr += pr[j]; si += pi[j];
        }
        sr += __shfl_xor(sr, 1); sr += __shfl_xor(sr, 2);
        si += __shfl_xor(si, 1); si += __shfl_xor(si, 2);
        const float rr = 1.f / sr, rri = 1.f / si;
        #pragma unroll
        for (int j = 0; j < 16; ++j) {
            const int c = cg + 4 * j;
            sW[0 * 4096 + c * 64 + e] = pr[j] * rr;   // W_r[c, e]
            sW[1 * 4096 + c * 64 + e] = pi[j] * rri;  // W_i[c, e]
        }
    }
    __syncthreads();

    // ---------------- Phase 3: U = X^T W (complex combine) ----------------
    {
        const int sg = tid & 31;                // s base lane
        const int eg = tid >> 5;                // 0..7
        const int e0 = eg * 8;
        float ur[4][8], ui[4][8];
        #pragma unroll
        for (int j = 0; j < 4; ++j)
            #pragma unroll
            for (int k = 0; k < 8; ++k) { ur[j][k] = 0.f; ui[j][k] = 0.f; }

        for (int c = 0; c < kC2; ++c) {
            float xrv[4], xiv[4];
            #pragma unroll
            for (int j = 0; j < 4; ++j) {
                xrv[j] = xb[(size_t)c * cstride + sg + 32 * j];
                xiv[j] = xb[(size_t)(c + kC2) * cstride + sg + 32 * j];
            }
            float wr[8], wi[8];
            #pragma unroll
            for (int k = 0; k < 8; ++k) {
                wr[k] = sW[c * 64 + e0 + k];
                wi[k] = sW[4096 + c * 64 + e0 + k];
            }
            #pragma unroll
            for (int j = 0; j < 4; ++j)
                #pragma unroll
                for (int k = 0; k < 8; ++k) {
                    ur[j][k] += xrv[j] * wr[k] - xiv[j] * wi[k];
                    ui[j][k] += xrv[j] * wi[k] + xiv[j] * wr[k];
                }
        }
        __syncthreads();   // everyone done reading sW/kq; overwrite with U
        #pragma unroll
        for (int j = 0; j < 4; ++j)
            #pragma unroll
            for (int k = 0; k < 8; ++k) {
                lds[(e0 + k) * 128 + sg + 32 * j]        = ur[j][k]; // U_r[e][s]
                lds[8192 + (e0 + k) * 128 + sg + 32 * j] = ui[j][k]; // U_i[e][s]
            }
    }
    __syncthreads();

    // ---------------- Phase 4: o = Wv U (+ bias), store ----------------
    {
        const int tg    = tid & 31;
        const int t4    = tg * 4;
        const int eslot = tid >> 5;             // 0..7
        float bvv[4];
        #pragma unroll
        for (int j = 0; j < 4; ++j) bvv[j] = bv[t4 + j];

        for (int estep = 0; estep < 8; ++estep) {
            const int e = eslot * 8 + estep;
            float or4[4] = {0.f, 0.f, 0.f, 0.f};
            float oi4[4] = {0.f, 0.f, 0.f, 0.f};
            for (int sc = 0; sc < kT; sc += 4) {
                const float4 u_r = *reinterpret_cast<const float4*>(&lds[e * 128 + sc]);
                const float4 u_i = *reinterpret_cast<const float4*>(&lds[8192 + e * 128 + sc]);
                #pragma unroll
                for (int j = 0; j < 4; ++j) {
                    const float4 wv = *reinterpret_cast<const float4*>(Wv + (t4 + j) * kT + sc);
                    or4[j] += wv.x * u_r.x + wv.y * u_r.y + wv.z * u_r.z + wv.w * u_r.w;
                    oi4[j] += wv.x * u_i.x + wv.y * u_i.y + wv.z * u_i.z + wv.w * u_i.w;
                }
            }
            float4 vr, vi;
            vr.x = or4[0]; vr.y = or4[1]; vr.z = or4[2]; vr.w = or4[3];
            vi.x = oi4[0] + 2.f * bvv[0];
            vi.y = oi4[1] + 2.f * bvv[1];
            vi.z = oi4[2] + 2.f * bvv[2];
            vi.w = oi4[3] + 2.f * bvv[3];
            // out[b, e, f, t] (real) and out[b, 64+e, f, t] (imag)
            *reinterpret_cast<float4*>(&out[(((size_t)b * kC + e) * kF + f) * kT + t4])        = vr;
            *reinterpret_cast<float4*>(&out[(((size_t)b * kC + kC2 + e) * kF + f) * kT + t4]) = vi;
        }
    }
}

extern "C" void kernel_launch(void* const* d_in, const int* in_sizes, int n_in,
                              void* d_out, int out_size, void* d_ws, size_t ws_size,
                              hipStream_t stream) {
    const float* x  = (const float*)d_in[0];
    const float* Wk = (const float*)d_in[1];
    const float* bk = (const float*)d_in[2];
    const float* Wq = (const float*)d_in[3];
    const float* bq = (const float*)d_in[4];
    const float* Wv = (const float*)d_in[5];
    const float* bv = (const float*)d_in[6];
    float* out = (float*)d_out;

    dim3 grid(kF, kB);   // 2048 blocks: one per (b, f)
    dim3 block(256);
    chanattn_f32<<<grid, block, 0, stream>>>(x, Wk, bk, Wq, bq, Wv, bv, out);
}

// Round 2
// 93.467 us; speedup vs baseline: 13.0920x; 13.0920x over previous
//
#include <hip/hip_runtime.h>

typedef __attribute__((ext_vector_type(8))) __bf16 bf16x8;
typedef __attribute__((ext_vector_type(8))) unsigned short ushort8;
typedef __attribute__((ext_vector_type(4))) unsigned short ushort4v;
typedef __attribute__((ext_vector_type(4))) float f32x4;

namespace {
constexpr int kB = 8, kC = 128, kF = 256, kT = 128;

// ---- LDS map (ushort elements, 24576 total = 48 KB) ----
// [0, 16384)      : XbfT[t][c]  (t=0..127, c=0..127), XOR-swizzled; later aliased by UT[ri][e][s]
// [16384, 24576)  : kqT[mat][c][d] (mat: 0=kr 1=ki 2=qr 3=qi), aliased later by sW[ri][e][c]
__device__ __forceinline__ int addrXT(int t, int c) { return t * 128 + (c ^ ((t & 7) << 3)); }
__device__ __forceinline__ int addrU(int ri, int e, int s) { return ri * 8192 + e * 128 + (s ^ ((e & 7) << 3)); }
__device__ __forceinline__ int addrK(int mat, int c, int d) { return 16384 + mat * 2048 + c * 32 + (d ^ ((c & 3) << 3)); }
__device__ __forceinline__ int addrW(int ri, int e, int c) { return 16384 + ri * 4096 + e * 64 + (c ^ ((e & 7) << 3)); }

__device__ __forceinline__ unsigned short b16(float f) {
    __bf16 h = (__bf16)f;
    return __builtin_bit_cast(unsigned short, h);
}

__device__ __forceinline__ bf16x8 ldfrag(const unsigned short* lds, int idx) {
    return __builtin_bit_cast(bf16x8, *(const ushort8*)(lds + idx));
}

__device__ __forceinline__ bf16x8 fneg(bf16x8 a) {
    ushort8 u = __builtin_bit_cast(ushort8, a);
    u ^= (unsigned short)0x8000;
    return __builtin_bit_cast(bf16x8, u);
}

// 8 consecutive fp32 from global -> bf16x8 fragment
__device__ __forceinline__ bf16x8 fragWg(const float* p) {
    f32x4 a = *(const f32x4*)p;
    f32x4 c = *(const f32x4*)(p + 4);
    bf16x8 r;
    r[0] = (__bf16)a[0]; r[1] = (__bf16)a[1]; r[2] = (__bf16)a[2]; r[3] = (__bf16)a[3];
    r[4] = (__bf16)c[0]; r[5] = (__bf16)c[1]; r[6] = (__bf16)c[2]; r[7] = (__bf16)c[3];
    return r;
}
} // namespace

__global__ __launch_bounds__(256, 3)
void chanattn_mfma(const float* __restrict__ x,
                   const float* __restrict__ Wk, const float* __restrict__ bk,
                   const float* __restrict__ Wq, const float* __restrict__ bq,
                   const float* __restrict__ Wv, const float* __restrict__ bv,
                   float* __restrict__ out)
{
    __shared__ __align__(16) unsigned short lds[24576];

    const int f = blockIdx.x, b = blockIdx.y;
    const int tid = threadIdx.x;
    const int lane = tid & 63;
    const int w = tid >> 6;          // wave id 0..3
    const int lr = lane & 15;        // fragment row/col lane index
    const int lg = lane >> 4;        // fragment k-group / output row-group
    const size_t cstr = (size_t)kF * kT;
    const float* xb = x + ((size_t)b * kC * kF + f) * kT; // xb[c*cstr + t]

    // ---------------- Phase 0: global x -> XbfT[t][c] (transposed, bf16, swizzled) ----------------
    {
        const int tcol = tid & 15;           // low t bits -> varies across lanes (bank spread)
        const int rrow = tid >> 4;           // 0..15
        #pragma unroll
        for (int p = 0; p < 8; ++p) {
            const int r = 16 * p + rrow;     // channel row c = 0..127
            const float* src = xb + (size_t)r * cstr;
            float v[8];
            #pragma unroll
            for (int q = 0; q < 8; ++q) v[q] = src[tcol + 16 * q];
            #pragma unroll
            for (int q = 0; q < 8; ++q) lds[addrXT(tcol + 16 * q, r)] = b16(v[q]);
        }
    }
    __syncthreads();

    // ---------------- Phase A: kqT[mat][c][d] = proj + bias (wave w -> mat w) ----------------
    {
        const float* Wm = (w < 2) ? Wk : Wq;
        const float* bm = (w < 2) ? bk : bq;
        const int crow0 = (w & 1) * 64;      // kr,qr use xr (c 0..63); ki,qi use xi (c 64..127)
        bf16x8 bw[2][4];
        #pragma unroll
        for (int dt = 0; dt < 2; ++dt)
            #pragma unroll
            for (int ks = 0; ks < 4; ++ks)
                bw[dt][ks] = fragWg(Wm + (size_t)(dt * 16 + lr) * kT + ks * 32 + 8 * lg);
        const float bias0 = bm[lr], bias1 = bm[16 + lr];

        #pragma unroll
        for (int ct = 0; ct < 4; ++ct) {
            f32x4 acc0 = {0.f, 0.f, 0.f, 0.f}, acc1 = {0.f, 0.f, 0.f, 0.f};
            #pragma unroll
            for (int ks = 0; ks < 4; ++ks) {
                bf16x8 a = fragWg(xb + (size_t)(crow0 + ct * 16 + lr) * cstr + ks * 32 + 8 * lg);
                acc0 = __builtin_amdgcn_mfma_f32_16x16x32_bf16(a, bw[0][ks], acc0, 0, 0, 0);
                acc1 = __builtin_amdgcn_mfma_f32_16x16x32_bf16(a, bw[1][ks], acc1, 0, 0, 0);
            }
            #pragma unroll
            for (int r = 0; r < 4; ++r) {
                const int c = ct * 16 + 4 * lg + r;
                lds[addrK(w, c, lr)]      = b16(acc0[r] + bias0);
                lds[addrK(w, c, 16 + lr)] = b16(acc1[r] + bias1);
            }
        }
    }
    __syncthreads();

    // ---------------- Phase B: P = K^T Q (complex) + softmax over c (wave w -> e-band 16w..16w+15) ----
    f32x4 pr[4], pi[4];
    float inv_r, inv_i;
    {
        const f32x4 zero = {0.f, 0.f, 0.f, 0.f};
        bf16x8 bqr = ldfrag(lds, addrK(2, 16 * w + lr, 8 * lg));
        bf16x8 bqi = ldfrag(lds, addrK(3, 16 * w + lr, 8 * lg));
        #pragma unroll
        for (int ct = 0; ct < 4; ++ct) {
            bf16x8 akr = ldfrag(lds, addrK(0, ct * 16 + lr, 8 * lg));
            bf16x8 aki = ldfrag(lds, addrK(1, ct * 16 + lr, 8 * lg));
            pr[ct] = __builtin_amdgcn_mfma_f32_16x16x32_bf16(akr, bqr, zero, 0, 0, 0);
            pr[ct] = __builtin_amdgcn_mfma_f32_16x16x32_bf16(fneg(aki), bqi, pr[ct], 0, 0, 0);
            pi[ct] = __builtin_amdgcn_mfma_f32_16x16x32_bf16(akr, bqi, zero, 0, 0, 0);
            pi[ct] = __builtin_amdgcn_mfma_f32_16x16x32_bf16(aki, bqr, pi[ct], 0, 0, 0);
        }
        float mr = -1e30f, mi = -1e30f;
        #pragma unroll
        for (int ct = 0; ct < 4; ++ct)
            #pragma unroll
            for (int r = 0; r < 4; ++r) { mr = fmaxf(mr, pr[ct][r]); mi = fmaxf(mi, pi[ct][r]); }
        mr = fmaxf(mr, __shfl_xor(mr, 16)); mr = fmaxf(mr, __shfl_xor(mr, 32));
        mi = fmaxf(mi, __shfl_xor(mi, 16)); mi = fmaxf(mi, __shfl_xor(mi, 32));
        float sr = 0.f, si = 0.f;
        #pragma unroll
        for (int ct = 0; ct < 4; ++ct)
            #pragma unroll
            for (int r = 0; r < 4; ++r) {
                float er = __expf(pr[ct][r] - mr); pr[ct][r] = er; sr += er;
                float ei = __expf(pi[ct][r] - mi); pi[ct][r] = ei; si += ei;
            }
        sr += __shfl_xor(sr, 16); sr += __shfl_xor(sr, 32);
        si += __shfl_xor(si, 16); si += __shfl_xor(si, 32);
        inv_r = 1.f / sr; inv_i = 1.f / si;
    }
    __syncthreads();   // all waves done reading kqT -> safe to overwrite with sW
    {
        const int e = 16 * w + lr;
        #pragma unroll
        for (int ct = 0; ct < 4; ++ct) {
            ushort4v wr4, wi4;
            #pragma unroll
            for (int r = 0; r < 4; ++r) {
                wr4[r] = b16(pr[ct][r] * inv_r);
                wi4[r] = b16(pi[ct][r] * inv_i);
            }
            *(ushort4v*)&lds[addrW(0, e, ct * 16 + 4 * lg)] = wr4;
            *(ushort4v*)&lds[addrW(1, e, ct * 16 + 4 * lg)] = wi4;
        }
    }
    __syncthreads();

    // ---------------- Phase C: UT[e][t] = sum_c W[c][e] X[c][t] (complex), accumulate in regs ----
    f32x4 uacc_r[8], uacc_i[8];
    {
        bf16x8 awr[2], awi[2], awin[2];
        #pragma unroll
        for (int ks = 0; ks < 2; ++ks) {
            awr[ks]  = ldfrag(lds, addrW(0, 16 * w + lr, ks * 32 + 8 * lg));
            awi[ks]  = ldfrag(lds, addrW(1, 16 * w + lr, ks * 32 + 8 * lg));
            awin[ks] = fneg(awi[ks]);
        }
        #pragma unroll
        for (int nt = 0; nt < 8; ++nt) {
            f32x4 ur = {0.f, 0.f, 0.f, 0.f}, ui = {0.f, 0.f, 0.f, 0.f};
            #pragma unroll
            for (int ks = 0; ks < 2; ++ks) {
                bf16x8 bxr = ldfrag(lds, addrXT(nt * 16 + lr, ks * 32 + 8 * lg));        // Xr
                bf16x8 bxi = ldfrag(lds, addrXT(nt * 16 + lr, 64 + ks * 32 + 8 * lg));   // Xi
                ur = __builtin_amdgcn_mfma_f32_16x16x32_bf16(awr[ks], bxr, ur, 0, 0, 0);
                ur = __builtin_amdgcn_mfma_f32_16x16x32_bf16(awin[ks], bxi, ur, 0, 0, 0);
                ui = __builtin_amdgcn_mfma_f32_16x16x32_bf16(awi[ks], bxr, ui, 0, 0, 0);
                ui = __builtin_amdgcn_mfma_f32_16x16x32_bf16(awr[ks], bxi, ui, 0, 0, 0);
            }
            uacc_r[nt] = ur; uacc_i[nt] = ui;
        }
    }
    __syncthreads();   // all waves done reading XbfT -> safe to overwrite with UT
    {
        #pragma unroll
        for (int nt = 0; nt < 8; ++nt)
            #pragma unroll
            for (int r = 0; r < 4; ++r) {
                const int e = 16 * w + 4 * lg + r;
                lds[addrU(0, e, nt * 16 + lr)] = b16(uacc_r[nt][r]);
                lds[addrU(1, e, nt * 16 + lr)] = b16(uacc_i[nt][r]);
            }
    }
    __syncthreads();

    // ---------------- Phase D: O[t'][e] = Wv * U (+2bv on imag), store fp32 ----------------
    {
        #pragma unroll
        for (int mi_ = 0; mi_ < 2; ++mi_) {
            const int mt = 2 * w + mi_;      // t'-tile 0..7
            bf16x8 av[4];
            #pragma unroll
            for (int ks = 0; ks < 4; ++ks)
                av[ks] = fragWg(Wv + (size_t)(mt * 16 + lr) * kT + ks * 32 + 8 * lg);
            float bvv[4];
            #pragma unroll
            for (int r = 0; r < 4; ++r) bvv[r] = 2.f * bv[mt * 16 + 4 * lg + r];

            #pragma unroll
            for (int et = 0; et < 4; ++et) {
                f32x4 aor = {0.f, 0.f, 0.f, 0.f}, aoi = {0.f, 0.f, 0.f, 0.f};
                #pragma unroll
                for (int ks = 0; ks < 4; ++ks) {
                    bf16x8 bur = ldfrag(lds, addrU(0, et * 16 + lr, ks * 32 + 8 * lg));
                    bf16x8 bui = ldfrag(lds, addrU(1, et * 16 + lr, ks * 32 + 8 * lg));
                    aor = __builtin_amdgcn_mfma_f32_16x16x32_bf16(av[ks], bur, aor, 0, 0, 0);
                    aoi = __builtin_amdgcn_mfma_f32_16x16x32_bf16(av[ks], bui, aoi, 0, 0, 0);
                }
                const int e = et * 16 + lr;
                const int tp0 = mt * 16 + 4 * lg;
                f32x4 vi;
                #pragma unroll
                for (int r = 0; r < 4; ++r) vi[r] = aoi[r] + bvv[r];
                *(f32x4*)(out + (((size_t)b * kC + e) * kF + f) * kT + tp0)      = aor;
                *(f32x4*)(out + (((size_t)b * kC + 64 + e) * kF + f) * kT + tp0) = vi;
            }
        }
    }
}

extern "C" void kernel_launch(void* const* d_in, const int* in_sizes, int n_in,
                              void* d_out, int out_size, void* d_ws, size_t ws_size,
                              hipStream_t stream) {
    const float* x  = (const float*)d_in[0];
    const float* Wk = (const float*)d_in[1];
    const float* bk = (const float*)d_in[2];
    const float* Wq = (const float*)d_in[3];
    const float* bq = (const float*)d_in[4];
    const float* Wv = (const float*)d_in[5];
    const float* bv = (const float*)d_in[6];
    float* out = (float*)d_out;

    dim3 grid(kF, kB);   // one block per (b, f)
    dim3 block(256);
    chanattn_mfma<<<grid, block, 0, stream>>>(x, Wk, bk, Wq, bq, Wv, bv, out);
}